// Round 18
// baseline (199.775 us; speedup 1.0000x reference)
//
#include <hip/hip_runtime.h>
#include <cstddef>
#include <cstdint>

// Mamba2 forward. bf16 MFMA GEMMs, 32x64 tiles, BK=128 (half the barriers,
// 2x MFMA per k-step), f32-W cvt-in-staging, bx-major XCD chunking.
// ydiag_off: 2 heads/block sharing the scores LDS slab.
// B=2 L=1024 DMODEL=768 DINNER=1536 NHEADS=192 P=8 N=64 CONVDIM=1664

typedef __bf16 bf16_t;
typedef bf16_t bf16x2 __attribute__((ext_vector_type(2)));
typedef bf16_t bf16x4 __attribute__((ext_vector_type(4)));
typedef bf16_t bf16x8 __attribute__((ext_vector_type(8)));
typedef float f32x4 __attribute__((ext_vector_type(4)));

// ---------------- ws layout (float units) ----------------
#define OFF_UB   ((size_t)0)                 // 2048*768 bf16
#define OFF_ZX   (OFF_UB  + 786432)          // 2048*3200 bf16
#define OFF_XBC  (OFF_ZX  + 3276800)         // 2048*1664 bf16
#define OFF_DT   (OFF_XBC + 1703936)         // 2*192*1024 f32
#define OFF_ACS  (OFF_DT  + 393216)          // 2*192*8*128 f32
#define OFF_SC   (OFF_ACS + 393216)          // 16*128*128 f32
#define OFF_ST   (OFF_SC  + 262144)          // 16*64*1536 f32 [bc][n][hp]
#define OFF_PV   (OFF_ST  + 1572864)         // 16*1536*64 bf16 [bc][hp][n]
#define OFF_Y    (OFF_PV  + 786432)          // 2048*1536 bf16
#define OFF_Y2B  (OFF_Y   + 1572864)         // 2048*1536 bf16

__device__ __forceinline__ float siluf(float x) { return x / (1.f + __expf(-x)); }

// ---------- transpose x (B,768,1024) -> ub bf16 (B*1024, 768) ----------
__global__ __launch_bounds__(256) void transpose_x_kernel(const float* __restrict__ x,
                                                          bf16_t* __restrict__ ub) {
  __shared__ float tile[32][33];
  int b = blockIdx.z;
  int d0 = blockIdx.x * 32, l0 = blockIdx.y * 32;
  int tx = threadIdx.x & 31, ty = threadIdx.x >> 5;
  for (int r = ty; r < 32; r += 8)
    tile[r][tx] = x[((size_t)(b * 768 + d0 + r)) * 1024 + l0 + tx];
  __syncthreads();
  for (int r = ty; r < 32; r += 8)
    ub[((size_t)(b * 1024 + l0 + r)) * 768 + d0 + tx] = (bf16_t)tile[tx][r];
}

// ---------- fused bf16 MFMA GEMM, 32x64 tile, BK=128 ----------
// MODE 0 (in-proj, K=768): cols<3200 -> zxb bf16; cols in [3200,3392):
//   dtb = softplus(C + dt_bias) (f32, t-contig); B rows >= 3392 zero-padded.
// MODE 1 (out-proj, K=1536): store f32 transposed to out(B,768,1024).
// LDS: A = 2 chunks of 32x64 bf16 (4KB each), B = 2 chunks of 64x64 (8KB
// each) -> 24KB; epilogue 32x69 f32 unioned.
template <int MODE>
__global__ __launch_bounds__(256) void gemm_fused(const bf16_t* __restrict__ A,
                                                  const float* __restrict__ B32,
                                                  void* __restrict__ Cv,
                                                  float* __restrict__ dtb,
                                                  const float* __restrict__ dt_bias,
                                                  int K) {
  __shared__ __align__(16) float smemf[6144];
  char* Abase = (char*)smemf;            // 2 x 4096 B
  char* Bbase = (char*)smemf + 8192;     // 2 x 8192 B
  float* eps = smemf;

  int tid = threadIdx.x;
  int wave = tid >> 6, lane = tid & 63;
  int wr = wave >> 1, wc = wave & 1;

  int gx = gridDim.x, gy = gridDim.y;
  int nwg = gx * gy;
  int flat = blockIdx.y * gx + blockIdx.x;
  int q = nwg >> 3;
  int cm = (flat & 7) * q + (flat >> 3);
  int bx = cm / gy, by = cm % gy;
  int m0 = by * 32, n0 = bx * 64;

  const bf16_t* Ag = A + (size_t)m0 * K;

  int aofs; const bf16_t* agp;
  {
    int r = tid >> 3, c = tid & 7;
    aofs = r * 128 + ((c ^ (r & 7)) << 4);
    agp = Ag + (size_t)r * K + c * 8;
  }
  int bofs[2]; const float* bgp[2]; bool bval[2];
#pragma unroll
  for (int i = 0; i < 2; ++i) {
    int id = i * 256 + tid;
    int r = id >> 3, c = id & 7;
    bofs[i] = r * 128 + ((c ^ (r & 7)) << 4);
    int grow = n0 + r;
    bval[i] = (MODE == 1) || (grow < 3392);
    bgp[i] = B32 + (size_t)grow * K + c * 8;
  }

  f32x4 acc[2] = {};
  uint4 areg[2];
  float4 b0[2][2], b1[2][2];  // [chunk][i]
#pragma unroll
  for (int ck = 0; ck < 2; ++ck) {
    areg[ck] = *(const uint4*)(agp + ck * 64);
#pragma unroll
    for (int i = 0; i < 2; ++i) {
      if (bval[i]) {
        b0[ck][i] = *(const float4*)(bgp[i] + ck * 64);
        b1[ck][i] = *(const float4*)(bgp[i] + ck * 64 + 4);
      } else {
        b0[ck][i] = make_float4(0.f, 0.f, 0.f, 0.f);
        b1[ck][i] = make_float4(0.f, 0.f, 0.f, 0.f);
      }
    }
  }

  for (int k0 = 0; k0 < K; k0 += 128) {
    __syncthreads();
#pragma unroll
    for (int ck = 0; ck < 2; ++ck) {
      *(uint4*)(Abase + ck * 4096 + aofs) = areg[ck];
#pragma unroll
      for (int i = 0; i < 2; ++i) {
        bf16x8 o = {(bf16_t)b0[ck][i].x, (bf16_t)b0[ck][i].y,
                    (bf16_t)b0[ck][i].z, (bf16_t)b0[ck][i].w,
                    (bf16_t)b1[ck][i].x, (bf16_t)b1[ck][i].y,
                    (bf16_t)b1[ck][i].z, (bf16_t)b1[ck][i].w};
        *(bf16x8*)(Bbase + ck * 8192 + bofs[i]) = o;
      }
    }
    __syncthreads();
    if (k0 + 128 < K) {
#pragma unroll
      for (int ck = 0; ck < 2; ++ck) {
        areg[ck] = *(const uint4*)(agp + k0 + 128 + ck * 64);
#pragma unroll
        for (int i = 0; i < 2; ++i) {
          if (bval[i]) {
            b0[ck][i] = *(const float4*)(bgp[i] + k0 + 128 + ck * 64);
            b1[ck][i] = *(const float4*)(bgp[i] + k0 + 128 + ck * 64 + 4);
          }
        }
      }
    }
#pragma unroll
    for (int ck = 0; ck < 2; ++ck) {
#pragma unroll
      for (int half = 0; half < 2; ++half) {
        int ca = half * 4 + (lane >> 4);
        bf16x8 af, bfr[2];
        {
          int Ra = wr * 16 + (lane & 15);
          af = *(const bf16x8*)(Abase + ck * 4096 + Ra * 128 + ((ca ^ (Ra & 7)) << 4));
        }
#pragma unroll
        for (int f = 0; f < 2; ++f) {
          int Rb = wc * 32 + f * 16 + (lane & 15);
          bfr[f] = *(const bf16x8*)(Bbase + ck * 8192 + Rb * 128 + ((ca ^ (Rb & 7)) << 4));
        }
#pragma unroll
        for (int j = 0; j < 2; ++j)
          acc[j] = __builtin_amdgcn_mfma_f32_16x16x32_bf16(af, bfr[j], acc[j], 0, 0, 0);
      }
    }
  }

  __syncthreads();
  {
    int rl = wr * 16 + ((lane >> 4) << 2);
#pragma unroll
    for (int j = 0; j < 2; ++j) {
      int col = wc * 32 + j * 16 + (lane & 15);
#pragma unroll
      for (int rr = 0; rr < 4; ++rr)
        eps[(rl + rr) * 69 + col] = acc[j][rr];
    }
  }
  __syncthreads();
  if (MODE == 0) {
    if (n0 < 3200) {
      bf16_t* Cb = (bf16_t*)Cv;
#pragma unroll
      for (int r = 0; r < 2; ++r) {
        int idx = tid + r * 256;
        int row = idx >> 4, c4 = (idx & 15) << 2;
        float4 v = *(const float4*)&eps[row * 69 + c4];
        bf16x4 o = {(bf16_t)v.x, (bf16_t)v.y, (bf16_t)v.z, (bf16_t)v.w};
        *(bf16x4*)&Cb[(size_t)(m0 + row) * 3200 + n0 + c4] = o;
      }
    } else {
      int b = m0 >> 10, t0 = m0 & 1023;
#pragma unroll
      for (int cg = 0; cg < 2; ++cg) {
        int col = cg * 32 + (tid >> 3);
        int h = n0 + col - 3200;
        if (h < 192) {
          int rr = (tid & 7) * 4;
          float bias = dt_bias[h];
          float vv[4];
#pragma unroll
          for (int k = 0; k < 4; ++k) {
            float v = eps[(rr + k) * 69 + col] + bias;
            vv[k] = (v > 20.f) ? v : log1pf(__expf(v));
          }
          *(float4*)&dtb[((size_t)(b * 192 + h)) * 1024 + t0 + rr] =
              make_float4(vv[0], vv[1], vv[2], vv[3]);
        }
      }
    }
  } else {
    float* Cf = (float*)Cv;
    int b = m0 >> 10, l0 = m0 & 1023;
#pragma unroll
    for (int cg = 0; cg < 2; ++cg) {
      int col = cg * 32 + (tid >> 3);
      int rr = (tid & 7) * 4;
      float4 v = make_float4(eps[(rr + 0) * 69 + col], eps[(rr + 1) * 69 + col],
                             eps[(rr + 2) * 69 + col], eps[(rr + 3) * 69 + col]);
      *(float4*)&Cf[((size_t)(b * 768 + n0 + col)) * 1024 + l0 + rr] = v;
    }
  }
}

// ---------- depthwise causal conv + bias + silu (bf16 in/out, 2ch/thr) ----------
__global__ __launch_bounds__(128) void conv_kernel(const bf16_t* __restrict__ zxb,
                                                   const float* __restrict__ conv_w,
                                                   const float* __restrict__ conv_b,
                                                   bf16_t* __restrict__ xBC) {
  int ch2 = blockIdx.x * 128 + threadIdx.x;
  if (ch2 >= 832) return;
  int ch = ch2 * 2;
  int m = blockIdx.y;
  int b = m >> 10, l = m & 1023;
  float a0 = conv_b[ch], a1 = conv_b[ch + 1];
  const bf16_t* base = zxb + (size_t)b * 1024 * 3200 + 1536 + ch;
#pragma unroll
  for (int j = 0; j < 4; ++j) {
    int tj = l - 3 + j;
    if (tj >= 0) {
      bf16x2 v = *(const bf16x2*)&base[(size_t)tj * 3200];
      a0 = fmaf(conv_w[ch * 4 + j], (float)v[0], a0);
      a1 = fmaf(conv_w[(ch + 1) * 4 + j], (float)v[1], a1);
    }
  }
  bf16x2 o = {(bf16_t)siluf(a0), (bf16_t)siluf(a1)};
  *(bf16x2*)&xBC[(size_t)m * 1664 + ch] = o;
}

// ---------- per-chunk inclusive scan of dA ----------
__global__ __launch_bounds__(128) void scan_kernel(const float* __restrict__ dtb,
                                                   const float* __restrict__ A_log,
                                                   float* __restrict__ Acs) {
  __shared__ float s[128];
  int idx = blockIdx.x;
  int c = idx & 7;
  int bh = idx >> 3;
  int h = bh % 192;
  int l = threadIdx.x;
  float Ah = -__expf(A_log[h]);
  float v = dtb[(size_t)bh * 1024 + c * 128 + l] * Ah;
  s[l] = v;
  __syncthreads();
  for (int off = 1; off < 128; off <<= 1) {
    float add = (l >= off) ? s[l - off] : 0.f;
    __syncthreads();
    s[l] += add;
    __syncthreads();
  }
  Acs[(size_t)idx * 128 + l] = s[l];
}

// ---------- scores[l,s] = sum_n Cm[l,n]*Bm[s,n]; grid (bc, 8 l-slabs) ----------
__global__ __launch_bounds__(256) void scores_kernel(const bf16_t* __restrict__ xBC,
                                                     float* __restrict__ scores) {
  __shared__ float Cs[16][16];
  __shared__ float Bs[16][128];
  int bc = blockIdx.x;
  int l0 = blockIdx.y * 16;
  const bf16_t* base = xBC + (size_t)bc * 128 * 1664;
  int tid = threadIdx.x;
  int tx = tid & 15, ty = tid >> 4;
  float acc[8] = {};
  for (int n0 = 0; n0 < 64; n0 += 16) {
    Cs[tid & 15][tid >> 4] =
        (float)base[(size_t)(l0 + (tid >> 4)) * 1664 + 1600 + n0 + (tid & 15)];
    for (int id = tid; id < 2048; id += 256) {
      int sr = id >> 4, nn = id & 15;
      Bs[nn][sr] = (float)base[(size_t)sr * 1664 + 1536 + n0 + nn];
    }
    __syncthreads();
#pragma unroll
    for (int nn = 0; nn < 16; ++nn) {
      float a = Cs[nn][ty];
#pragma unroll
      for (int j = 0; j < 8; ++j)
        acc[j] = fmaf(a, Bs[nn][tx * 8 + j], acc[j]);
    }
    __syncthreads();
  }
  float* srow = scores + (size_t)bc * 16384 + (size_t)(l0 + ty) * 128;
#pragma unroll
  for (int j = 0; j < 8; ++j) srow[tx * 8 + j] = acc[j];
}

// ---------- chunk states via MFMA, per (bc, 16-head tile) ----------
__global__ __launch_bounds__(256) void states_mfma_kernel(
    const bf16_t* __restrict__ xBC, const float* __restrict__ dtb,
    const float* __restrict__ Acs, float* __restrict__ st2) {
  __shared__ bf16_t Asm[64 * 128];
  __shared__ bf16_t Wsm[128 * 128];
  __shared__ float dcoef[16][128];
  int tile = blockIdx.x;
  int bc = blockIdx.y;
  int c = bc & 7, b = bc >> 3;
  int hg0 = tile * 16;
  int tid = threadIdx.x;
  int wave = tid >> 6, lane = tid & 63;

#pragma unroll
  for (int i = 0; i < 8; ++i) {
    int id = tid + i * 256;
    int hh = id >> 7, s = id & 127;
    int h = hg0 + hh;
    const float* ar = Acs + (((size_t)(b * 192 + h)) * 8 + c) * 128;
    float dv = dtb[((size_t)(b * 192 + h)) * 1024 + c * 128 + s];
    dcoef[hh][s] = dv * __expf(ar[127] - ar[s]);
  }
#pragma unroll
  for (int i = 0; i < 32; ++i) {
    int id = tid + i * 256;
    int s = id >> 6, n = id & 63;
    float v = (float)xBC[((size_t)(bc * 128 + s)) * 1664 + 1536 + n];
    int byte = n * 256 + (((s >> 3) ^ (n & 7)) << 4) + (s & 7) * 2;
    *(bf16_t*)((char*)Asm + byte) = (bf16_t)v;
  }
  __syncthreads();
#pragma unroll
  for (int i = 0; i < 64; ++i) {
    int id = tid + i * 256;
    int s = id >> 7, hp = id & 127;
    float v = (float)xBC[((size_t)(bc * 128 + s)) * 1664 + hg0 * 8 + hp] * dcoef[hp >> 3][s];
    int byte = hp * 256 + (((s >> 3) ^ (hp & 7)) << 4) + (s & 7) * 2;
    *(bf16_t*)((char*)Wsm + byte) = (bf16_t)v;
  }
  __syncthreads();

  f32x4 acc[4][2] = {};
#pragma unroll
  for (int ks = 0; ks < 4; ++ks) {
    int cc = ks * 4 + (lane >> 4);
    bf16x8 af[4], bfr[2];
#pragma unroll
    for (int i = 0; i < 4; ++i) {
      int Ra = i * 16 + (lane & 15);
      af[i] = *(const bf16x8*)((const char*)Asm + Ra * 256 + ((cc ^ (Ra & 7)) << 4));
    }
#pragma unroll
    for (int j = 0; j < 2; ++j) {
      int Rb = wave * 32 + j * 16 + (lane & 15);
      bfr[j] = *(const bf16x8*)((const char*)Wsm + Rb * 256 + ((cc ^ (Rb & 7)) << 4));
    }
#pragma unroll
    for (int i = 0; i < 4; ++i)
#pragma unroll
      for (int j = 0; j < 2; ++j)
        acc[i][j] = __builtin_amdgcn_mfma_f32_16x16x32_bf16(af[i], bfr[j], acc[i][j], 0, 0, 0);
  }
#pragma unroll
  for (int i = 0; i < 4; ++i)
#pragma unroll
    for (int j = 0; j < 2; ++j) {
      int n = i * 16 + ((lane >> 4) << 2);
      int col = tile * 128 + wave * 32 + j * 16 + (lane & 15);
      float* sp = st2 + (size_t)bc * 98304 + (size_t)n * 1536 + col;
#pragma unroll
      for (int rr = 0; rr < 4; ++rr) sp[(size_t)rr * 1536] = acc[i][j][rr];
    }
}

// ---------- inter-chunk recurrence; st f32 [bc][n][hp] -> pv bf16 [bc][hp][n] ----------
__global__ __launch_bounds__(512) void recur_kernel(const float* __restrict__ Acs,
                                                    const float* __restrict__ states,
                                                    bf16_t* __restrict__ prev) {
  int bh = blockIdx.x;
  int b = bh / 192, h = bh % 192;
  int tid = threadIdx.x;
  int p = tid >> 6, n = tid & 63;
  float s_run = 0.f;
  for (int c = 0; c < 8; ++c) {
    size_t base = (size_t)(b * 8 + c) * 98304;
    prev[base + (size_t)(h * 8 + p) * 64 + n] = (bf16_t)s_run;
    float dAs = Acs[(((size_t)(b * 192 + h)) * 8 + c) * 128 + 127];
    s_run = s_run * __expf(dAs) + states[base + (size_t)n * 1536 + h * 8 + p];
  }
}

// ---------- Y = Y_diag + Y_off + D*x via MFMA, 2 heads/block, 128 thr ----------
__global__ __launch_bounds__(128) void ydiag_off_kernel(
    const bf16_t* __restrict__ xBC, const float* __restrict__ dtb,
    const float* __restrict__ Acs, const float* __restrict__ scores,
    const bf16_t* __restrict__ pv, const float* __restrict__ Dvec,
    bf16_t* __restrict__ Y) {
  __shared__ float sc_s[128][36];
  __shared__ float xdtT[2][8][132];
  __shared__ float acs_s[2][128];
  __shared__ bf16_t pv_s[2][512];
  int idx = blockIdx.x;
  int hp2 = idx % 96;
  int bc = idx / 96;
  int h0 = hp2 * 2;
  int c = bc & 7, b = bc >> 3;
  int tid = threadIdx.x;
  int lane = tid & 63, wid = tid >> 6;

#pragma unroll
  for (int hh = 0; hh < 2; ++hh) {
    int h = h0 + hh;
    acs_s[hh][tid] = Acs[(((size_t)(b * 192 + h)) * 8 + c) * 128 + tid];
    {
      int p = tid & 7, s0 = (tid >> 3) * 8;
      const float* dtr = dtb + ((size_t)(b * 192 + h)) * 1024 + c * 128;
#pragma unroll
      for (int j = 0; j < 8; ++j) {
        int s = s0 + j;
        xdtT[hh][p][s] = (float)xBC[((size_t)(bc * 128 + s)) * 1664 + h * 8 + p] * dtr[s];
      }
    }
    {
      const bf16_t* pb = pv + (size_t)bc * 98304 + (size_t)h * 512;
      *(bf16x4*)&pv_s[hh][tid * 4] = *(const bf16x4*)&pb[tid * 4];
    }
  }

  f32x4 acc[2][4] = {};
  const float* sall = scores + (size_t)bc * 16384;
  for (int ks = 0; ks < 4; ++ks) {
    __syncthreads();
#pragma unroll
    for (int i = 0; i < 8; ++i) {
      int id = tid + i * 128;
      int l = id >> 3, c4 = (id & 7) * 4;
      *(float4*)&sc_s[l][c4] = *(const float4*)&sall[(size_t)l * 128 + ks * 32 + c4];
    }
    __syncthreads();

#pragma unroll
    for (int hh = 0; hh < 2; ++hh) {
      bf16x8 bfv;
      {
        int p = lane & 7;
        int sb = (lane >> 4) * 8;
        float4 v0 = *(const float4*)&xdtT[hh][p][ks * 32 + sb];
        float4 v1 = *(const float4*)&xdtT[hh][p][ks * 32 + sb + 4];
        bfv[0] = (bf16_t)v0.x; bfv[1] = (bf16_t)v0.y; bfv[2] = (bf16_t)v0.z; bfv[3] = (bf16_t)v0.w;
        bfv[4] = (bf16_t)v1.x; bfv[5] = (bf16_t)v1.y; bfv[6] = (bf16_t)v1.z; bfv[7] = (bf16_t)v1.w;
      }
#pragma unroll
      for (int mf = 0; mf < 4; ++mf) {
        int lbase = (mf * 2 + wid) * 16;
        if (ks * 32 > lbase + 15) continue;
        int l = lbase + (lane & 15);
        float al = acs_s[hh][l];
        int sb = (lane >> 4) * 8;
        int sg = ks * 32 + sb;
        float4 s0 = *(const float4*)&sc_s[l][sb];
        float4 s1 = *(const float4*)&sc_s[l][sb + 4];
        float4 e0 = *(const float4*)&acs_s[hh][sg];
        float4 e1 = *(const float4*)&acs_s[hh][sg + 4];
        float sv[8] = {s0.x, s0.y, s0.z, s0.w, s1.x, s1.y, s1.z, s1.w};
        float ev[8] = {e0.x, e0.y, e0.z, e0.w, e1.x, e1.y, e1.z, e1.w};
        bf16x8 af;
#pragma unroll
        for (int j = 0; j < 8; ++j) {
          float v = sv[j] * __expf(al - ev[j]);
          af[j] = (bf16_t)((sg + j <= l) ? v : 0.f);
        }
        acc[hh][mf] = __builtin_amdgcn_mfma_f32_16x16x32_bf16(af, bfv, acc[hh][mf], 0, 0, 0);
      }
    }
  }

  __syncthreads();
#pragma unroll
  for (int ks2 = 0; ks2 < 2; ++ks2) {
    int kbase = ks2 * 32 + (lane >> 4) * 8;
#pragma unroll
    for (int hh = 0; hh < 2; ++hh) {
      bf16x8 bv;
      {
        int p = lane & 15;
        if (p < 8) {
          bv = *(const bf16x8*)&pv_s[hh][p * 64 + kbase];
        } else {
          bv = (bf16x8)(bf16_t)0.f;
        }
      }
#pragma unroll
      for (int mf = 0; mf < 4; ++mf) {
        int l = (mf * 2 + wid) * 16 + (lane & 15);
        float el = __expf(acs_s[hh][l]);
        bf16x8 c8 = *(const bf16x8*)&xBC[((size_t)(bc * 128 + l)) * 1664 + 1600 + kbase];
        bf16x8 af;
#pragma unroll
        for (int j = 0; j < 8; ++j) af[j] = (bf16_t)((float)c8[j] * el);
        acc[hh][mf] = __builtin_amdgcn_mfma_f32_16x16x32_bf16(af, bv, acc[hh][mf], 0, 0, 0);
      }
    }
  }

  int p = lane & 15;
  if (p < 8) {
#pragma unroll
    for (int hh = 0; hh < 2; ++hh) {
      int h = h0 + hh;
      float Dh = Dvec[h];
      int rg = (lane >> 4) * 4;
#pragma unroll
      for (int mf = 0; mf < 4; ++mf) {
        int lbase = (mf * 2 + wid) * 16;
        bf16_t* yp = Y + ((size_t)(bc * 128 + lbase + rg)) * 1536 + h * 8 + p;
#pragma unroll
        for (int rr = 0; rr < 4; ++rr) {
          float xv = (float)xBC[((size_t)(bc * 128 + lbase + rg + rr)) * 1664 + h * 8 + p];
          yp[(size_t)rr * 1536] = (bf16_t)(acc[hh][mf][rr] + Dh * xv);
        }
      }
    }
  }
}

// ---------- gate with silu(z) + RMSNorm -> y2 bf16 ----------
__global__ __launch_bounds__(256) void gatenorm_kernel(const bf16_t* __restrict__ Yb,
                                                       const bf16_t* __restrict__ zxb,
                                                       const float* __restrict__ norm_w,
                                                       bf16_t* __restrict__ y2b) {
  int m = blockIdx.x;
  int tid = threadIdx.x;
  int base = tid * 6;
  const bf16_t* yrow = Yb + (size_t)m * 1536 + base;
  const bf16_t* zrow = zxb + (size_t)m * 3200 + base;
  float vals[6];
  float ss = 0.f;
#pragma unroll
  for (int j = 0; j < 3; ++j) {
    bf16x2 yv = *(const bf16x2*)&yrow[j * 2];
    bf16x2 zv = *(const bf16x2*)&zrow[j * 2];
    float v0 = (float)yv[0] * siluf((float)zv[0]);
    float v1 = (float)yv[1] * siluf((float)zv[1]);
    vals[j * 2] = v0; vals[j * 2 + 1] = v1;
    ss = fmaf(v0, v0, fmaf(v1, v1, ss));
  }
#pragma unroll
  for (int off = 32; off > 0; off >>= 1) ss += __shfl_down(ss, off);
  __shared__ float red[4];
  int lane = tid & 63, wid = tid >> 6;
  if (lane == 0) red[wid] = ss;
  __syncthreads();
  float tot = red[0] + red[1] + red[2] + red[3];
  float scale = rsqrtf(tot * (1.f / 1536.f) + 1e-5f);
  bf16_t* orow = y2b + (size_t)m * 1536 + base;
#pragma unroll
  for (int j = 0; j < 3; ++j) {
    bf16x2 o = {(bf16_t)(vals[j * 2] * scale * norm_w[base + j * 2]),
                (bf16_t)(vals[j * 2 + 1] * scale * norm_w[base + j * 2 + 1])};
    *(bf16x2*)&orow[j * 2] = o;
  }
}

extern "C" void kernel_launch(void* const* d_in, const int* in_sizes, int n_in,
                              void* d_out, int out_size, void* d_ws, size_t ws_size,
                              hipStream_t stream) {
  const float* x = (const float*)d_in[0];
  const float* W_in = (const float*)d_in[1];
  const float* conv_w = (const float*)d_in[2];
  const float* conv_b = (const float*)d_in[3];
  const float* dt_bias = (const float*)d_in[4];
  const float* A_log = (const float*)d_in[5];
  const float* Dvec = (const float*)d_in[6];
  const float* norm_w = (const float*)d_in[7];
  const float* W_out = (const float*)d_in[8];
  float* out = (float*)d_out;
  float* ws = (float*)d_ws;

  bf16_t* ub = (bf16_t*)(ws + OFF_UB);
  bf16_t* zxb = (bf16_t*)(ws + OFF_ZX);
  bf16_t* xBC = (bf16_t*)(ws + OFF_XBC);
  float* dtb = ws + OFF_DT;
  float* Acs = ws + OFF_ACS;
  float* sc = ws + OFF_SC;
  float* st = ws + OFF_ST;
  bf16_t* pv = (bf16_t*)(ws + OFF_PV);
  bf16_t* Yb = (bf16_t*)(ws + OFF_Y);
  bf16_t* y2b = (bf16_t*)(ws + OFF_Y2B);

  transpose_x_kernel<<<dim3(24, 32, 2), 256, 0, stream>>>(x, ub);
  gemm_fused<0><<<dim3(54, 64), 256, 0, stream>>>(ub, W_in, zxb, dtb, dt_bias, 768);
  conv_kernel<<<dim3(7, 2048), 128, 0, stream>>>(zxb, conv_w, conv_b, xBC);
  scan_kernel<<<3072, 128, 0, stream>>>(dtb, A_log, Acs);
  scores_kernel<<<dim3(16, 8), 256, 0, stream>>>(xBC, sc);
  states_mfma_kernel<<<dim3(12, 16), 256, 0, stream>>>(xBC, dtb, Acs, st);
  recur_kernel<<<384, 512, 0, stream>>>(Acs, st, pv);
  ydiag_off_kernel<<<1536, 128, 0, stream>>>(xBC, dtb, Acs, sc, pv, Dvec, Yb);
  gatenorm_kernel<<<2048, 256, 0, stream>>>(Yb, zxb, norm_w, y2b);
  gemm_fused<1><<<dim3(12, 64), 256, 0, stream>>>(y2b, W_out, out, nullptr, nullptr, 1536);
}

// Round 19
// 151.337 us; speedup vs baseline: 1.3201x; 1.3201x over previous
//
#include <hip/hip_runtime.h>
#include <cstddef>
#include <cstdint>

// Mamba2 forward — round-17 configuration (best verified: 152.0 us).
// bf16 MFMA GEMMs, 32x64 tiles, BK=64 (BK=128 regressed: FETCH x3, r18),
// f32-W cvt-in-staging, bx-major XCD chunking, bf16 intermediates.
// ydiag_off: 2 heads/block sharing the scores LDS slab.
// B=2 L=1024 DMODEL=768 DINNER=1536 NHEADS=192 P=8 N=64 CONVDIM=1664

typedef __bf16 bf16_t;
typedef bf16_t bf16x2 __attribute__((ext_vector_type(2)));
typedef bf16_t bf16x4 __attribute__((ext_vector_type(4)));
typedef bf16_t bf16x8 __attribute__((ext_vector_type(8)));
typedef float f32x4 __attribute__((ext_vector_type(4)));

// ---------------- ws layout (float units) ----------------
#define OFF_UB   ((size_t)0)                 // 2048*768 bf16
#define OFF_ZX   (OFF_UB  + 786432)          // 2048*3200 bf16
#define OFF_XBC  (OFF_ZX  + 3276800)         // 2048*1664 bf16
#define OFF_DT   (OFF_XBC + 1703936)         // 2*192*1024 f32
#define OFF_ACS  (OFF_DT  + 393216)          // 2*192*8*128 f32
#define OFF_SC   (OFF_ACS + 393216)          // 16*128*128 f32
#define OFF_ST   (OFF_SC  + 262144)          // 16*64*1536 f32 [bc][n][hp]
#define OFF_PV   (OFF_ST  + 1572864)         // 16*1536*64 bf16 [bc][hp][n]
#define OFF_Y    (OFF_PV  + 786432)          // 2048*1536 bf16
#define OFF_Y2B  (OFF_Y   + 1572864)         // 2048*1536 bf16

__device__ __forceinline__ float siluf(float x) { return x / (1.f + __expf(-x)); }

// ---------- transpose x (B,768,1024) -> ub bf16 (B*1024, 768) ----------
__global__ __launch_bounds__(256) void transpose_x_kernel(const float* __restrict__ x,
                                                          bf16_t* __restrict__ ub) {
  __shared__ float tile[32][33];
  int b = blockIdx.z;
  int d0 = blockIdx.x * 32, l0 = blockIdx.y * 32;
  int tx = threadIdx.x & 31, ty = threadIdx.x >> 5;
  for (int r = ty; r < 32; r += 8)
    tile[r][tx] = x[((size_t)(b * 768 + d0 + r)) * 1024 + l0 + tx];
  __syncthreads();
  for (int r = ty; r < 32; r += 8)
    ub[((size_t)(b * 1024 + l0 + r)) * 768 + d0 + tx] = (bf16_t)tile[tx][r];
}

// ---------- fused bf16 MFMA GEMM, 32x64 tile, BK=64 ----------
// MODE 0 (in-proj, K=768): cols<3200 -> zxb bf16; cols in [3200,3392):
//   dtb = softplus(C + dt_bias) (f32, t-contig); B rows >= 3392 zero-padded.
// MODE 1 (out-proj, K=1536): store f32 transposed to out(B,768,1024).
template <int MODE>
__global__ __launch_bounds__(256) void gemm_fused(const bf16_t* __restrict__ A,
                                                  const float* __restrict__ B32,
                                                  void* __restrict__ Cv,
                                                  float* __restrict__ dtb,
                                                  const float* __restrict__ dt_bias,
                                                  int K) {
  __shared__ __align__(16) float smemf[3072];
  bf16_t* Asmem = (bf16_t*)smemf;
  bf16_t* Bsmem = Asmem + 32 * 64;
  float* eps = smemf;

  int tid = threadIdx.x;
  int wave = tid >> 6, lane = tid & 63;
  int wr = wave >> 1, wc = wave & 1;

  int gx = gridDim.x, gy = gridDim.y;
  int nwg = gx * gy;
  int flat = blockIdx.y * gx + blockIdx.x;
  int q = nwg >> 3;
  int cm = (flat & 7) * q + (flat >> 3);
  int bx = cm / gy, by = cm % gy;
  int m0 = by * 32, n0 = bx * 64;

  const bf16_t* Ag = A + (size_t)m0 * K;

  int aofs; const bf16_t* agp;
  {
    int r = tid >> 3, c = tid & 7;
    aofs = r * 128 + ((c ^ (r & 7)) << 4);
    agp = Ag + (size_t)r * K + c * 8;
  }
  int bofs[2]; const float* bgp[2]; bool bval[2];
#pragma unroll
  for (int i = 0; i < 2; ++i) {
    int id = i * 256 + tid;
    int r = id >> 3, c = id & 7;
    bofs[i] = r * 128 + ((c ^ (r & 7)) << 4);
    int grow = n0 + r;
    bval[i] = (MODE == 1) || (grow < 3392);
    bgp[i] = B32 + (size_t)grow * K + c * 8;
  }

  f32x4 acc[2] = {};
  uint4 areg;
  float4 b0[2], b1[2];
  areg = *(const uint4*)(agp);
#pragma unroll
  for (int i = 0; i < 2; ++i) {
    if (bval[i]) {
      b0[i] = *(const float4*)(bgp[i]);
      b1[i] = *(const float4*)(bgp[i] + 4);
    } else {
      b0[i] = make_float4(0.f, 0.f, 0.f, 0.f);
      b1[i] = make_float4(0.f, 0.f, 0.f, 0.f);
    }
  }

  for (int k0 = 0; k0 < K; k0 += 64) {
    __syncthreads();
    *(uint4*)((char*)Asmem + aofs) = areg;
#pragma unroll
    for (int i = 0; i < 2; ++i) {
      bf16x8 o = {(bf16_t)b0[i].x, (bf16_t)b0[i].y, (bf16_t)b0[i].z, (bf16_t)b0[i].w,
                  (bf16_t)b1[i].x, (bf16_t)b1[i].y, (bf16_t)b1[i].z, (bf16_t)b1[i].w};
      *(bf16x8*)((char*)Bsmem + bofs[i]) = o;
    }
    __syncthreads();
    if (k0 + 64 < K) {
      areg = *(const uint4*)(agp + k0 + 64);
#pragma unroll
      for (int i = 0; i < 2; ++i) {
        if (bval[i]) {
          b0[i] = *(const float4*)(bgp[i] + k0 + 64);
          b1[i] = *(const float4*)(bgp[i] + k0 + 68);
        }
      }
    }
#pragma unroll
    for (int half = 0; half < 2; ++half) {
      int ca = half * 4 + (lane >> 4);
      bf16x8 af, bfr[2];
      {
        int Ra = wr * 16 + (lane & 15);
        af = *(const bf16x8*)((const char*)Asmem + Ra * 128 + ((ca ^ (Ra & 7)) << 4));
      }
#pragma unroll
      for (int f = 0; f < 2; ++f) {
        int Rb = wc * 32 + f * 16 + (lane & 15);
        bfr[f] = *(const bf16x8*)((const char*)Bsmem + Rb * 128 + ((ca ^ (Rb & 7)) << 4));
      }
#pragma unroll
      for (int j = 0; j < 2; ++j)
        acc[j] = __builtin_amdgcn_mfma_f32_16x16x32_bf16(af, bfr[j], acc[j], 0, 0, 0);
    }
  }

  __syncthreads();
  {
    int rl = wr * 16 + ((lane >> 4) << 2);
#pragma unroll
    for (int j = 0; j < 2; ++j) {
      int col = wc * 32 + j * 16 + (lane & 15);
#pragma unroll
      for (int rr = 0; rr < 4; ++rr)
        eps[(rl + rr) * 69 + col] = acc[j][rr];
    }
  }
  __syncthreads();
  if (MODE == 0) {
    if (n0 < 3200) {
      bf16_t* Cb = (bf16_t*)Cv;
#pragma unroll
      for (int r = 0; r < 2; ++r) {
        int idx = tid + r * 256;
        int row = idx >> 4, c4 = (idx & 15) << 2;
        float4 v = *(const float4*)&eps[row * 69 + c4];
        bf16x4 o = {(bf16_t)v.x, (bf16_t)v.y, (bf16_t)v.z, (bf16_t)v.w};
        *(bf16x4*)&Cb[(size_t)(m0 + row) * 3200 + n0 + c4] = o;
      }
    } else {
      int b = m0 >> 10, t0 = m0 & 1023;
#pragma unroll
      for (int cg = 0; cg < 2; ++cg) {
        int col = cg * 32 + (tid >> 3);
        int h = n0 + col - 3200;
        if (h < 192) {
          int rr = (tid & 7) * 4;
          float bias = dt_bias[h];
          float vv[4];
#pragma unroll
          for (int k = 0; k < 4; ++k) {
            float v = eps[(rr + k) * 69 + col] + bias;
            vv[k] = (v > 20.f) ? v : log1pf(__expf(v));
          }
          *(float4*)&dtb[((size_t)(b * 192 + h)) * 1024 + t0 + rr] =
              make_float4(vv[0], vv[1], vv[2], vv[3]);
        }
      }
    }
  } else {
    float* Cf = (float*)Cv;
    int b = m0 >> 10, l0 = m0 & 1023;
#pragma unroll
    for (int cg = 0; cg < 2; ++cg) {
      int col = cg * 32 + (tid >> 3);
      int rr = (tid & 7) * 4;
      float4 v = make_float4(eps[(rr + 0) * 69 + col], eps[(rr + 1) * 69 + col],
                             eps[(rr + 2) * 69 + col], eps[(rr + 3) * 69 + col]);
      *(float4*)&Cf[((size_t)(b * 768 + n0 + col)) * 1024 + l0 + rr] = v;
    }
  }
}

// ---------- depthwise causal conv + bias + silu (bf16 in/out, 2ch/thr) ----------
__global__ __launch_bounds__(128) void conv_kernel(const bf16_t* __restrict__ zxb,
                                                   const float* __restrict__ conv_w,
                                                   const float* __restrict__ conv_b,
                                                   bf16_t* __restrict__ xBC) {
  int ch2 = blockIdx.x * 128 + threadIdx.x;
  if (ch2 >= 832) return;
  int ch = ch2 * 2;
  int m = blockIdx.y;
  int b = m >> 10, l = m & 1023;
  float a0 = conv_b[ch], a1 = conv_b[ch + 1];
  const bf16_t* base = zxb + (size_t)b * 1024 * 3200 + 1536 + ch;
#pragma unroll
  for (int j = 0; j < 4; ++j) {
    int tj = l - 3 + j;
    if (tj >= 0) {
      bf16x2 v = *(const bf16x2*)&base[(size_t)tj * 3200];
      a0 = fmaf(conv_w[ch * 4 + j], (float)v[0], a0);
      a1 = fmaf(conv_w[(ch + 1) * 4 + j], (float)v[1], a1);
    }
  }
  bf16x2 o = {(bf16_t)siluf(a0), (bf16_t)siluf(a1)};
  *(bf16x2*)&xBC[(size_t)m * 1664 + ch] = o;
}

// ---------- per-chunk inclusive scan of dA ----------
__global__ __launch_bounds__(128) void scan_kernel(const float* __restrict__ dtb,
                                                   const float* __restrict__ A_log,
                                                   float* __restrict__ Acs) {
  __shared__ float s[128];
  int idx = blockIdx.x;
  int c = idx & 7;
  int bh = idx >> 3;
  int h = bh % 192;
  int l = threadIdx.x;
  float Ah = -__expf(A_log[h]);
  float v = dtb[(size_t)bh * 1024 + c * 128 + l] * Ah;
  s[l] = v;
  __syncthreads();
  for (int off = 1; off < 128; off <<= 1) {
    float add = (l >= off) ? s[l - off] : 0.f;
    __syncthreads();
    s[l] += add;
    __syncthreads();
  }
  Acs[(size_t)idx * 128 + l] = s[l];
}

// ---------- scores[l,s] = sum_n Cm[l,n]*Bm[s,n]; grid (bc, 8 l-slabs) ----------
__global__ __launch_bounds__(256) void scores_kernel(const bf16_t* __restrict__ xBC,
                                                     float* __restrict__ scores) {
  __shared__ float Cs[16][16];
  __shared__ float Bs[16][128];
  int bc = blockIdx.x;
  int l0 = blockIdx.y * 16;
  const bf16_t* base = xBC + (size_t)bc * 128 * 1664;
  int tid = threadIdx.x;
  int tx = tid & 15, ty = tid >> 4;
  float acc[8] = {};
  for (int n0 = 0; n0 < 64; n0 += 16) {
    Cs[tid & 15][tid >> 4] =
        (float)base[(size_t)(l0 + (tid >> 4)) * 1664 + 1600 + n0 + (tid & 15)];
    for (int id = tid; id < 2048; id += 256) {
      int sr = id >> 4, nn = id & 15;
      Bs[nn][sr] = (float)base[(size_t)sr * 1664 + 1536 + n0 + nn];
    }
    __syncthreads();
#pragma unroll
    for (int nn = 0; nn < 16; ++nn) {
      float a = Cs[nn][ty];
#pragma unroll
      for (int j = 0; j < 8; ++j)
        acc[j] = fmaf(a, Bs[nn][tx * 8 + j], acc[j]);
    }
    __syncthreads();
  }
  float* srow = scores + (size_t)bc * 16384 + (size_t)(l0 + ty) * 128;
#pragma unroll
  for (int j = 0; j < 8; ++j) srow[tx * 8 + j] = acc[j];
}

// ---------- chunk states via MFMA, per (bc, 16-head tile) ----------
__global__ __launch_bounds__(256) void states_mfma_kernel(
    const bf16_t* __restrict__ xBC, const float* __restrict__ dtb,
    const float* __restrict__ Acs, float* __restrict__ st2) {
  __shared__ bf16_t Asm[64 * 128];
  __shared__ bf16_t Wsm[128 * 128];
  __shared__ float dcoef[16][128];
  int tile = blockIdx.x;
  int bc = blockIdx.y;
  int c = bc & 7, b = bc >> 3;
  int hg0 = tile * 16;
  int tid = threadIdx.x;
  int wave = tid >> 6, lane = tid & 63;

#pragma unroll
  for (int i = 0; i < 8; ++i) {
    int id = tid + i * 256;
    int hh = id >> 7, s = id & 127;
    int h = hg0 + hh;
    const float* ar = Acs + (((size_t)(b * 192 + h)) * 8 + c) * 128;
    float dv = dtb[((size_t)(b * 192 + h)) * 1024 + c * 128 + s];
    dcoef[hh][s] = dv * __expf(ar[127] - ar[s]);
  }
#pragma unroll
  for (int i = 0; i < 32; ++i) {
    int id = tid + i * 256;
    int s = id >> 6, n = id & 63;
    float v = (float)xBC[((size_t)(bc * 128 + s)) * 1664 + 1536 + n];
    int byte = n * 256 + (((s >> 3) ^ (n & 7)) << 4) + (s & 7) * 2;
    *(bf16_t*)((char*)Asm + byte) = (bf16_t)v;
  }
  __syncthreads();
#pragma unroll
  for (int i = 0; i < 64; ++i) {
    int id = tid + i * 256;
    int s = id >> 7, hp = id & 127;
    float v = (float)xBC[((size_t)(bc * 128 + s)) * 1664 + hg0 * 8 + hp] * dcoef[hp >> 3][s];
    int byte = hp * 256 + (((s >> 3) ^ (hp & 7)) << 4) + (s & 7) * 2;
    *(bf16_t*)((char*)Wsm + byte) = (bf16_t)v;
  }
  __syncthreads();

  f32x4 acc[4][2] = {};
#pragma unroll
  for (int ks = 0; ks < 4; ++ks) {
    int cc = ks * 4 + (lane >> 4);
    bf16x8 af[4], bfr[2];
#pragma unroll
    for (int i = 0; i < 4; ++i) {
      int Ra = i * 16 + (lane & 15);
      af[i] = *(const bf16x8*)((const char*)Asm + Ra * 256 + ((cc ^ (Ra & 7)) << 4));
    }
#pragma unroll
    for (int j = 0; j < 2; ++j) {
      int Rb = wave * 32 + j * 16 + (lane & 15);
      bfr[j] = *(const bf16x8*)((const char*)Wsm + Rb * 256 + ((cc ^ (Rb & 7)) << 4));
    }
#pragma unroll
    for (int i = 0; i < 4; ++i)
#pragma unroll
      for (int j = 0; j < 2; ++j)
        acc[i][j] = __builtin_amdgcn_mfma_f32_16x16x32_bf16(af[i], bfr[j], acc[i][j], 0, 0, 0);
  }
#pragma unroll
  for (int i = 0; i < 4; ++i)
#pragma unroll
    for (int j = 0; j < 2; ++j) {
      int n = i * 16 + ((lane >> 4) << 2);
      int col = tile * 128 + wave * 32 + j * 16 + (lane & 15);
      float* sp = st2 + (size_t)bc * 98304 + (size_t)n * 1536 + col;
#pragma unroll
      for (int rr = 0; rr < 4; ++rr) sp[(size_t)rr * 1536] = acc[i][j][rr];
    }
}

// ---------- inter-chunk recurrence; st f32 [bc][n][hp] -> pv bf16 [bc][hp][n] ----------
__global__ __launch_bounds__(512) void recur_kernel(const float* __restrict__ Acs,
                                                    const float* __restrict__ states,
                                                    bf16_t* __restrict__ prev) {
  int bh = blockIdx.x;
  int b = bh / 192, h = bh % 192;
  int tid = threadIdx.x;
  int p = tid >> 6, n = tid & 63;
  float s_run = 0.f;
  for (int c = 0; c < 8; ++c) {
    size_t base = (size_t)(b * 8 + c) * 98304;
    prev[base + (size_t)(h * 8 + p) * 64 + n] = (bf16_t)s_run;
    float dAs = Acs[(((size_t)(b * 192 + h)) * 8 + c) * 128 + 127];
    s_run = s_run * __expf(dAs) + states[base + (size_t)n * 1536 + h * 8 + p];
  }
}

// ---------- Y = Y_diag + Y_off + D*x via MFMA, 2 heads/block, 128 thr ----------
// grid: 16 bc x 96 head-pairs = 1536 blocks. sc_s slab shared across 2 heads.
__global__ __launch_bounds__(128) void ydiag_off_kernel(
    const bf16_t* __restrict__ xBC, const float* __restrict__ dtb,
    const float* __restrict__ Acs, const float* __restrict__ scores,
    const bf16_t* __restrict__ pv, const float* __restrict__ Dvec,
    bf16_t* __restrict__ Y) {
  __shared__ float sc_s[128][36];
  __shared__ float xdtT[2][8][132];
  __shared__ float acs_s[2][128];
  __shared__ bf16_t pv_s[2][512];
  int idx = blockIdx.x;
  int hp2 = idx % 96;
  int bc = idx / 96;
  int h0 = hp2 * 2;
  int c = bc & 7, b = bc >> 3;
  int tid = threadIdx.x;
  int lane = tid & 63, wid = tid >> 6;

#pragma unroll
  for (int hh = 0; hh < 2; ++hh) {
    int h = h0 + hh;
    acs_s[hh][tid] = Acs[(((size_t)(b * 192 + h)) * 8 + c) * 128 + tid];
    {
      int p = tid & 7, s0 = (tid >> 3) * 8;
      const float* dtr = dtb + ((size_t)(b * 192 + h)) * 1024 + c * 128;
#pragma unroll
      for (int j = 0; j < 8; ++j) {
        int s = s0 + j;
        xdtT[hh][p][s] = (float)xBC[((size_t)(bc * 128 + s)) * 1664 + h * 8 + p] * dtr[s];
      }
    }
    {
      const bf16_t* pb = pv + (size_t)bc * 98304 + (size_t)h * 512;
      *(bf16x4*)&pv_s[hh][tid * 4] = *(const bf16x4*)&pb[tid * 4];
    }
  }

  f32x4 acc[2][4] = {};
  const float* sall = scores + (size_t)bc * 16384;
  for (int ks = 0; ks < 4; ++ks) {
    __syncthreads();
#pragma unroll
    for (int i = 0; i < 8; ++i) {
      int id = tid + i * 128;
      int l = id >> 3, c4 = (id & 7) * 4;
      *(float4*)&sc_s[l][c4] = *(const float4*)&sall[(size_t)l * 128 + ks * 32 + c4];
    }
    __syncthreads();

#pragma unroll
    for (int hh = 0; hh < 2; ++hh) {
      bf16x8 bfv;
      {
        int p = lane & 7;
        int sb = (lane >> 4) * 8;
        float4 v0 = *(const float4*)&xdtT[hh][p][ks * 32 + sb];
        float4 v1 = *(const float4*)&xdtT[hh][p][ks * 32 + sb + 4];
        bfv[0] = (bf16_t)v0.x; bfv[1] = (bf16_t)v0.y; bfv[2] = (bf16_t)v0.z; bfv[3] = (bf16_t)v0.w;
        bfv[4] = (bf16_t)v1.x; bfv[5] = (bf16_t)v1.y; bfv[6] = (bf16_t)v1.z; bfv[7] = (bf16_t)v1.w;
      }
#pragma unroll
      for (int mf = 0; mf < 4; ++mf) {
        int lbase = (mf * 2 + wid) * 16;
        if (ks * 32 > lbase + 15) continue;
        int l = lbase + (lane & 15);
        float al = acs_s[hh][l];
        int sb = (lane >> 4) * 8;
        int sg = ks * 32 + sb;
        float4 s0 = *(const float4*)&sc_s[l][sb];
        float4 s1 = *(const float4*)&sc_s[l][sb + 4];
        float4 e0 = *(const float4*)&acs_s[hh][sg];
        float4 e1 = *(const float4*)&acs_s[hh][sg + 4];
        float sv[8] = {s0.x, s0.y, s0.z, s0.w, s1.x, s1.y, s1.z, s1.w};
        float ev[8] = {e0.x, e0.y, e0.z, e0.w, e1.x, e1.y, e1.z, e1.w};
        bf16x8 af;
#pragma unroll
        for (int j = 0; j < 8; ++j) {
          float v = sv[j] * __expf(al - ev[j]);
          af[j] = (bf16_t)((sg + j <= l) ? v : 0.f);
        }
        acc[hh][mf] = __builtin_amdgcn_mfma_f32_16x16x32_bf16(af, bfv, acc[hh][mf], 0, 0, 0);
      }
    }
  }

  __syncthreads();
#pragma unroll
  for (int ks2 = 0; ks2 < 2; ++ks2) {
    int kbase = ks2 * 32 + (lane >> 4) * 8;
#pragma unroll
    for (int hh = 0; hh < 2; ++hh) {
      bf16x8 bv;
      {
        int p = lane & 15;
        if (p < 8) {
          bv = *(const bf16x8*)&pv_s[hh][p * 64 + kbase];
        } else {
          bv = (bf16x8)(bf16_t)0.f;
        }
      }
#pragma unroll
      for (int mf = 0; mf < 4; ++mf) {
        int l = (mf * 2 + wid) * 16 + (lane & 15);
        float el = __expf(acs_s[hh][l]);
        bf16x8 c8 = *(const bf16x8*)&xBC[((size_t)(bc * 128 + l)) * 1664 + 1600 + kbase];
        bf16x8 af;
#pragma unroll
        for (int j = 0; j < 8; ++j) af[j] = (bf16_t)((float)c8[j] * el);
        acc[hh][mf] = __builtin_amdgcn_mfma_f32_16x16x32_bf16(af, bv, acc[hh][mf], 0, 0, 0);
      }
    }
  }

  int p = lane & 15;
  if (p < 8) {
#pragma unroll
    for (int hh = 0; hh < 2; ++hh) {
      int h = h0 + hh;
      float Dh = Dvec[h];
      int rg = (lane >> 4) * 4;
#pragma unroll
      for (int mf = 0; mf < 4; ++mf) {
        int lbase = (mf * 2 + wid) * 16;
        bf16_t* yp = Y + ((size_t)(bc * 128 + lbase + rg)) * 1536 + h * 8 + p;
#pragma unroll
        for (int rr = 0; rr < 4; ++rr) {
          float xv = (float)xBC[((size_t)(bc * 128 + lbase + rg + rr)) * 1664 + h * 8 + p];
          yp[(size_t)rr * 1536] = (bf16_t)(acc[hh][mf][rr] + Dh * xv);
        }
      }
    }
  }
}

// ---------- gate with silu(z) + RMSNorm -> y2 bf16 ----------
__global__ __launch_bounds__(256) void gatenorm_kernel(const bf16_t* __restrict__ Yb,
                                                       const bf16_t* __restrict__ zxb,
                                                       const float* __restrict__ norm_w,
                                                       bf16_t* __restrict__ y2b) {
  int m = blockIdx.x;
  int tid = threadIdx.x;
  int base = tid * 6;
  const bf16_t* yrow = Yb + (size_t)m * 1536 + base;
  const bf16_t* zrow = zxb + (size_t)m * 3200 + base;
  float vals[6];
  float ss = 0.f;
#pragma unroll
  for (int j = 0; j < 3; ++j) {
    bf16x2 yv = *(const bf16x2*)&yrow[j * 2];
    bf16x2 zv = *(const bf16x2*)&zrow[j * 2];
    float v0 = (float)yv[0] * siluf((float)zv[0]);
    float v1 = (float)yv[1] * siluf((float)zv[1]);
    vals[j * 2] = v0; vals[j * 2 + 1] = v1;
    ss = fmaf(v0, v0, fmaf(v1, v1, ss));
  }
#pragma unroll
  for (int off = 32; off > 0; off >>= 1) ss += __shfl_down(ss, off);
  __shared__ float red[4];
  int lane = tid & 63, wid = tid >> 6;
  if (lane == 0) red[wid] = ss;
  __syncthreads();
  float tot = red[0] + red[1] + red[2] + red[3];
  float scale = rsqrtf(tot * (1.f / 1536.f) + 1e-5f);
  bf16_t* orow = y2b + (size_t)m * 1536 + base;
#pragma unroll
  for (int j = 0; j < 3; ++j) {
    bf16x2 o = {(bf16_t)(vals[j * 2] * scale * norm_w[base + j * 2]),
                (bf16_t)(vals[j * 2 + 1] * scale * norm_w[base + j * 2 + 1])};
    *(bf16x2*)&orow[j * 2] = o;
  }
}

extern "C" void kernel_launch(void* const* d_in, const int* in_sizes, int n_in,
                              void* d_out, int out_size, void* d_ws, size_t ws_size,
                              hipStream_t stream) {
  const float* x = (const float*)d_in[0];
  const float* W_in = (const float*)d_in[1];
  const float* conv_w = (const float*)d_in[2];
  const float* conv_b = (const float*)d_in[3];
  const float* dt_bias = (const float*)d_in[4];
  const float* A_log = (const float*)d_in[5];
  const float* Dvec = (const float*)d_in[6];
  const float* norm_w = (const float*)d_in[7];
  const float* W_out = (const float*)d_in[8];
  float* out = (float*)d_out;
  float* ws = (float*)d_ws;

  bf16_t* ub = (bf16_t*)(ws + OFF_UB);
  bf16_t* zxb = (bf16_t*)(ws + OFF_ZX);
  bf16_t* xBC = (bf16_t*)(ws + OFF_XBC);
  float* dtb = ws + OFF_DT;
  float* Acs = ws + OFF_ACS;
  float* sc = ws + OFF_SC;
  float* st = ws + OFF_ST;
  bf16_t* pv = (bf16_t*)(ws + OFF_PV);
  bf16_t* Yb = (bf16_t*)(ws + OFF_Y);
  bf16_t* y2b = (bf16_t*)(ws + OFF_Y2B);

  transpose_x_kernel<<<dim3(24, 32, 2), 256, 0, stream>>>(x, ub);
  gemm_fused<0><<<dim3(54, 64), 256, 0, stream>>>(ub, W_in, zxb, dtb, dt_bias, 768);
  conv_kernel<<<dim3(7, 2048), 128, 0, stream>>>(zxb, conv_w, conv_b, xBC);
  scan_kernel<<<3072, 128, 0, stream>>>(dtb, A_log, Acs);
  scores_kernel<<<dim3(16, 8), 256, 0, stream>>>(xBC, sc);
  states_mfma_kernel<<<dim3(12, 16), 256, 0, stream>>>(xBC, dtb, Acs, st);
  recur_kernel<<<384, 512, 0, stream>>>(Acs, st, pv);
  ydiag_off_kernel<<<1536, 128, 0, stream>>>(xBC, dtb, Acs, sc, pv, Dvec, Yb);
  gatenorm_kernel<<<2048, 256, 0, stream>>>(Yb, zxb, norm_w, y2b);
  gemm_fused<1><<<dim3(12, 64), 256, 0, stream>>>(y2b, W_out, out, nullptr, nullptr, 1536);
}